// Round 14
// baseline (166.210 us; speedup 1.0000x reference)
//
#include <hip/hip_runtime.h>

#define N_NODES 16384
#define N_EDGES 65536

typedef float f32x16 __attribute__((ext_vector_type(16)));
typedef float f32x8  __attribute__((ext_vector_type(8)));
typedef float f32x4  __attribute__((ext_vector_type(4)));
typedef float f32x2  __attribute__((ext_vector_type(2)));

__device__ __forceinline__ float rfl_f(float v) {
    int i = __builtin_amdgcn_readfirstlane(__builtin_bit_cast(int, v));
    return __builtin_bit_cast(float, i);
}

// h1[n,o] = bias1[o] + sum_{i<8} x[n,i] * root1[i,o]
__global__ void k_node1(const float* __restrict__ x, const float* __restrict__ root1,
                        const float* __restrict__ bias1, float* __restrict__ h1) {
    int t = blockIdx.x * blockDim.x + threadIdx.x;   // t in [0, N*64)
    int n = t >> 6, o = t & 63;
    float acc = bias1[o];
#pragma unroll
    for (int i = 0; i < 8; ++i)
        acc = fmaf(x[n * 8 + i], root1[i * 64 + o], acc);
    h1[t] = acc;
}

// layer-1 edge kernel v12: wave per EDGE-PAIR, software-pipelined x-row loads
__global__ __launch_bounds__(256)
void k_edge1(const float* __restrict__ x, const int* __restrict__ ei,
             const float* __restrict__ ea, const float* __restrict__ A1,
             const float* __restrict__ b1, float* __restrict__ h1) {
    int lane = threadIdx.x & 63;
    f32x8 W0, W1, BB;
#pragma unroll
    for (int i = 0; i < 8; ++i) {
        W0[i] = A1[i * 64 + lane];
        W1[i] = A1[512 + i * 64 + lane];
        BB[i] = b1[i * 64 + lane];
    }
    asm volatile("" : "+v"(W0), "+v"(W1), "+v"(BB));

    int wid = blockIdx.x * (blockDim.x >> 6) + (threadIdx.x >> 6);
    int nw = gridDim.x * (blockDim.x >> 6);

    f32x8 ha, hb;
    // prologue: meta(0), issue x-rows(0), prefetch meta(1)
    int p0 = wid;
    int2   dst_c = ((const int2*)(ei + N_EDGES))[p0];
    float4 ea_c  = ((const float4*)ea)[p0];
    {
        int2 s = ((const int2*)ei)[p0];
        int s0 = __builtin_amdgcn_readfirstlane(s.x);
        int s1 = __builtin_amdgcn_readfirstlane(s.y);
        const float* xp0 = x + (size_t)s0 * 8;
        const float* xp1 = x + (size_t)s1 * 8;
        asm volatile("s_load_dwordx8 %0, %2, 0x0\n\t"
                     "s_load_dwordx8 %1, %3, 0x0"
                     : "=&s"(ha), "=&s"(hb) : "s"(xp0), "s"(xp1));
    }
    int pn = p0 + nw; if (pn > N_EDGES / 2 - 1) pn = N_EDGES / 2 - 1;
    int2   src_n = ((const int2*)ei)[pn];
    int2   dst_n = ((const int2*)(ei + N_EDGES))[pn];
    float4 ea_n  = ((const float4*)ea)[pn];

#pragma clang loop unroll(disable)
    for (int p = wid; p < N_EDGES / 2; p += nw) {
        int s0n = __builtin_amdgcn_readfirstlane(src_n.x);
        int s1n = __builtin_amdgcn_readfirstlane(src_n.y);
        const float* xpn0 = x + (size_t)s0n * 8;
        const float* xpn1 = x + (size_t)s1n * 8;

        asm volatile("s_waitcnt lgkmcnt(0)" : "+s"(ha), "+s"(hb));

        f32x2 e00 = {ea_c.x, ea_c.x}, e01 = {ea_c.y, ea_c.y};
        f32x2 e10 = {ea_c.z, ea_c.z}, e11 = {ea_c.w, ea_c.w};
        const f32x2 z2 = {0.f, 0.f};
        f32x2 acc0 = z2, acc1 = z2;
#pragma unroll
        for (int k = 0; k < 4; ++k) {
            f32x2 w0p = {W0[2 * k], W0[2 * k + 1]};
            f32x2 w1p = {W1[2 * k], W1[2 * k + 1]};
            f32x2 bp  = {BB[2 * k], BB[2 * k + 1]};
            f32x2 wv0 = __builtin_elementwise_max(
                __builtin_elementwise_fma(e01, w1p,
                    __builtin_elementwise_fma(e00, w0p, bp)), z2);
            f32x2 h0p = {ha[2 * k], ha[2 * k + 1]};
            acc0 = __builtin_elementwise_fma(h0p, wv0, acc0);
            f32x2 wv1 = __builtin_elementwise_max(
                __builtin_elementwise_fma(e11, w1p,
                    __builtin_elementwise_fma(e10, w0p, bp)), z2);
            f32x2 h1p = {hb[2 * k], hb[2 * k + 1]};
            acc1 = __builtin_elementwise_fma(h1p, wv1, acc1);
        }
        // issue next pair's x-rows (latency hides under atomics + meta + next drain)
        asm volatile("s_load_dwordx8 %0, %2, 0x0\n\t"
                     "s_load_dwordx8 %1, %3, 0x0"
                     : "=&s"(ha), "=&s"(hb) : "s"(xpn0), "s"(xpn1));

        atomicAdd(&h1[(size_t)dst_c.x * 64 + lane], acc0[0] + acc0[1]);
        atomicAdd(&h1[(size_t)dst_c.y * 64 + lane], acc1[0] + acc1[1]);

        dst_c = dst_n; ea_c = ea_n;
        int pn2 = p + 2 * nw; if (pn2 > N_EDGES / 2 - 1) pn2 = N_EDGES / 2 - 1;
        src_n = ((const int2*)ei)[pn2];
        dst_n = ((const int2*)(ei + N_EDGES))[pn2];
        ea_n  = ((const float4*)ea)[pn2];
    }
}

// out[n,o] = bias2[o] + sum_{i<64} h1[n,i] * root2[i,o]  (pipelined h loads)
__global__ __launch_bounds__(256)
void k_node2(const float* __restrict__ h1, const float* __restrict__ root2,
             const float* __restrict__ bias2, float* __restrict__ out) {
    int lane = threadIdx.x & 63;
    f32x16 R0, R1, R2, R3;
#pragma unroll
    for (int i = 0; i < 16; ++i) {
        R0[i] = root2[(i)      * 64 + lane];
        R1[i] = root2[(16 + i) * 64 + lane];
        R2[i] = root2[(32 + i) * 64 + lane];
        R3[i] = root2[(48 + i) * 64 + lane];
    }
    asm volatile("" : "+v"(R0), "+v"(R1), "+v"(R2), "+v"(R3));
    float bias = bias2[lane];

    int wid = blockIdx.x * (blockDim.x >> 6) + (threadIdx.x >> 6);
    int nw = gridDim.x * (blockDim.x >> 6);

    f32x16 h0, h1v, h2, h3;
    int nu_c = __builtin_amdgcn_readfirstlane(wid);   // launder (threadIdx-derived)
    {
        const float* hp = h1 + (size_t)nu_c * 64;
        asm volatile("s_load_dwordx16 %0, %4, 0x0\n\t"
                     "s_load_dwordx16 %1, %4, 0x40\n\t"
                     "s_load_dwordx16 %2, %4, 0x80\n\t"
                     "s_load_dwordx16 %3, %4, 0xc0"
                     : "=&s"(h0), "=&s"(h1v), "=&s"(h2), "=&s"(h3) : "s"(hp));
    }
#pragma clang loop unroll(disable)
    for (int n = wid; n < N_NODES; n += nw) {
        int nn = n + nw; if (nn >= N_NODES) nn = n;    // clamp: harmless reload
        int nu_n = __builtin_amdgcn_readfirstlane(nn);
        const float* hpn = h1 + (size_t)nu_n * 64;

        asm volatile("s_waitcnt lgkmcnt(0)"
                     : "+s"(h0), "+s"(h1v), "+s"(h2), "+s"(h3));
        f32x2 accp = {bias, 0.f};
#pragma unroll
        for (int k = 0; k < 8; ++k) {
            f32x2 hp0 = {h0[2 * k], h0[2 * k + 1]};
            f32x2 rp0 = {R0[2 * k], R0[2 * k + 1]};
            accp = __builtin_elementwise_fma(hp0, rp0, accp);
            f32x2 hp1 = {h1v[2 * k], h1v[2 * k + 1]};
            f32x2 rp1 = {R1[2 * k], R1[2 * k + 1]};
            accp = __builtin_elementwise_fma(hp1, rp1, accp);
            f32x2 hp2 = {h2[2 * k], h2[2 * k + 1]};
            f32x2 rp2 = {R2[2 * k], R2[2 * k + 1]};
            accp = __builtin_elementwise_fma(hp2, rp2, accp);
            f32x2 hp3 = {h3[2 * k], h3[2 * k + 1]};
            f32x2 rp3 = {R3[2 * k], R3[2 * k + 1]};
            accp = __builtin_elementwise_fma(hp3, rp3, accp);
        }
        // issue next row's loads before the store/loop-tail
        asm volatile("s_load_dwordx16 %0, %4, 0x0\n\t"
                     "s_load_dwordx16 %1, %4, 0x40\n\t"
                     "s_load_dwordx16 %2, %4, 0x80\n\t"
                     "s_load_dwordx16 %3, %4, 0xc0"
                     : "=&s"(h0), "=&s"(h1v), "=&s"(h2), "=&s"(h3) : "s"(hpn));
        out[(size_t)nu_c * 64 + lane] = accp[0] + accp[1];
        nu_c = nu_n;
    }
}

// layer-2 edge kernel v12: QUARTER-slice (16 i's per block).
// LDS 15.4KB (not the occupancy cap), hoisted weights only 48 VGPR -> ~5 waves/SIMD
// for HBM-latency hiding on the h-row gathers (FETCH evidence: h reads miss L2).
// h per edge = one s_load_dwordx16; pipelined issue-after-compute.
__global__ __launch_bounds__(256)
void k_edge2(const float* __restrict__ h1, const int* __restrict__ ei,
             const float* __restrict__ ea, const float* __restrict__ A2,
             const float* __restrict__ b2, float* __restrict__ out) {
    __shared__ __align__(16) float WT[3 * 64 * 20];   // 15360 B, row stride 20 dwords
    int q = blockIdx.x & 3;                           // block's i-quarter (uniform)
    for (int j = threadIdx.x; j < 1024; j += 256) {   // 16 i x 64 o, coalesced in o
        int il = j >> 6, o = j & 63;
        int ig = q * 16 + il;
        WT[o * 20 + il]        = A2[ig * 64 + o];
        WT[1280 + o * 20 + il] = A2[4096 + ig * 64 + o];
        WT[2560 + o * 20 + il] = b2[ig * 64 + o];
    }
    __syncthreads();

    int lane = threadIdx.x & 63;
    unsigned laddr = (unsigned)(uintptr_t)WT + lane * 80;

    // hoisted loop-invariant weight reads (ONCE per wave; asm outputs can't remat)
    f32x4 wa[4], wb[4], wc[4];
    asm volatile(
        "ds_read_b128 %0, %12 offset:0\n\t"
        "ds_read_b128 %1, %12 offset:16\n\t"
        "ds_read_b128 %2, %12 offset:32\n\t"
        "ds_read_b128 %3, %12 offset:48\n\t"
        "ds_read_b128 %4, %12 offset:5120\n\t"
        "ds_read_b128 %5, %12 offset:5136\n\t"
        "ds_read_b128 %6, %12 offset:5152\n\t"
        "ds_read_b128 %7, %12 offset:5168\n\t"
        "ds_read_b128 %8, %12 offset:10240\n\t"
        "ds_read_b128 %9, %12 offset:10256\n\t"
        "ds_read_b128 %10, %12 offset:10272\n\t"
        "ds_read_b128 %11, %12 offset:10288"
        : "=&v"(wa[0]), "=&v"(wa[1]), "=&v"(wa[2]), "=&v"(wa[3]),
          "=&v"(wb[0]), "=&v"(wb[1]), "=&v"(wb[2]), "=&v"(wb[3]),
          "=&v"(wc[0]), "=&v"(wc[1]), "=&v"(wc[2]), "=&v"(wc[3])
        : "v"(laddr));
    asm volatile("s_waitcnt lgkmcnt(0)"
        : "+v"(wa[0]), "+v"(wa[1]), "+v"(wa[2]), "+v"(wa[3]),
          "+v"(wb[0]), "+v"(wb[1]), "+v"(wb[2]), "+v"(wb[3]),
          "+v"(wc[0]), "+v"(wc[1]), "+v"(wc[2]), "+v"(wc[3]));

    int base = q * 16;                                 // block-uniform (SGPR-safe)
    int g = blockIdx.x >> 2;                           // 0..511
    int wslot = g * 4 + (threadIdx.x >> 6);            // 0..2047
    const int STRIDE = 2048;                           // 16 iters/wave

    f32x16 ha, hc;                    // quarter h-rows: edge0, edge1
    // prologue: meta(0), issue h(0), prefetch meta(1)
    int p0 = wslot;
    int2   dst_c = ((const int2*)(ei + N_EDGES))[p0];
    float4 ea_c  = ((const float4*)ea)[p0];
    {
        int2 s = ((const int2*)ei)[p0];
        int s0 = __builtin_amdgcn_readfirstlane(s.x);
        int s1 = __builtin_amdgcn_readfirstlane(s.y);
        const float* hp0 = h1 + (size_t)s0 * 64 + base;
        const float* hp1 = h1 + (size_t)s1 * 64 + base;
        asm volatile("s_load_dwordx16 %0, %2, 0x0\n\t"
                     "s_load_dwordx16 %1, %3, 0x0"
                     : "=&s"(ha), "=&s"(hc) : "s"(hp0), "s"(hp1));
    }
    int pn = p0 + STRIDE; if (pn > N_EDGES / 2 - 1) pn = N_EDGES / 2 - 1;
    int2   src_n = ((const int2*)ei)[pn];
    int2   dst_n = ((const int2*)(ei + N_EDGES))[pn];
    float4 ea_n  = ((const float4*)ea)[pn];

#pragma clang loop unroll(disable)
    for (int p = wslot; p < N_EDGES / 2; p += STRIDE) {
        int s0n = __builtin_amdgcn_readfirstlane(src_n.x);
        int s1n = __builtin_amdgcn_readfirstlane(src_n.y);
        const float* hpn0 = h1 + (size_t)s0n * 64 + base;
        const float* hpn1 = h1 + (size_t)s1n * 64 + base;

        asm volatile("s_waitcnt lgkmcnt(0)" : "+s"(ha), "+s"(hc));

        f32x2 e00 = {ea_c.x, ea_c.x}, e01 = {ea_c.y, ea_c.y};
        f32x2 e10 = {ea_c.z, ea_c.z}, e11 = {ea_c.w, ea_c.w};
        const f32x2 z2 = {0.f, 0.f};
        f32x2 acc0 = z2, acc1 = z2;
#pragma unroll
        for (int qq = 0; qq < 4; ++qq) {
#pragma unroll
            for (int k = 0; k < 2; ++k) {
                f32x2 w0p = {wa[qq][2 * k], wa[qq][2 * k + 1]};
                f32x2 w1p = {wb[qq][2 * k], wb[qq][2 * k + 1]};
                f32x2 bp  = {wc[qq][2 * k], wc[qq][2 * k + 1]};
                f32x2 wv0 = __builtin_elementwise_max(
                    __builtin_elementwise_fma(e01, w1p,
                        __builtin_elementwise_fma(e00, w0p, bp)), z2);
                f32x2 h0p = {ha[qq * 4 + 2 * k], ha[qq * 4 + 2 * k + 1]};
                acc0 = __builtin_elementwise_fma(h0p, wv0, acc0);
                f32x2 wv1 = __builtin_elementwise_max(
                    __builtin_elementwise_fma(e11, w1p,
                        __builtin_elementwise_fma(e10, w0p, bp)), z2);
                f32x2 h1p = {hc[qq * 4 + 2 * k], hc[qq * 4 + 2 * k + 1]};
                acc1 = __builtin_elementwise_fma(h1p, wv1, acc1);
            }
        }
        // issue next pair's h quarter-rows (hides under atomics + meta + next drain)
        asm volatile("s_load_dwordx16 %0, %2, 0x0\n\t"
                     "s_load_dwordx16 %1, %3, 0x0"
                     : "=&s"(ha), "=&s"(hc) : "s"(hpn0), "s"(hpn1));

        atomicAdd(&out[(size_t)dst_c.x * 64 + lane], acc0[0] + acc0[1]);
        atomicAdd(&out[(size_t)dst_c.y * 64 + lane], acc1[0] + acc1[1]);

        dst_c = dst_n; ea_c = ea_n;
        int pn2 = p + 2 * STRIDE; if (pn2 > N_EDGES / 2 - 1) pn2 = N_EDGES / 2 - 1;
        src_n = ((const int2*)ei)[pn2];
        dst_n = ((const int2*)(ei + N_EDGES))[pn2];
        ea_n  = ((const float4*)ea)[pn2];
    }
}

extern "C" void kernel_launch(void* const* d_in, const int* in_sizes, int n_in,
                              void* d_out, int out_size, void* d_ws, size_t ws_size,
                              hipStream_t stream) {
    const float* x     = (const float*)d_in[0];
    const int*   ei    = (const int*)d_in[1];
    const float* ea    = (const float*)d_in[2];
    const float* A1    = (const float*)d_in[3];
    const float* b1    = (const float*)d_in[4];
    const float* A2    = (const float*)d_in[5];
    const float* b2    = (const float*)d_in[6];
    const float* root1 = (const float*)d_in[7];
    const float* bias1 = (const float*)d_in[8];
    const float* root2 = (const float*)d_in[9];
    const float* bias2 = (const float*)d_in[10];
    float* out = (float*)d_out;
    float* h1  = (float*)d_ws;        // N*64 floats = 4 MB scratch

    // 1) h1 = bias1 + x @ root1   (fully initializes ws accumulator)
    k_node1<<<N_NODES * 64 / 256, 256, 0, stream>>>(x, root1, bias1, h1);
    // 2) h1 += scatter-add of layer-1 edge messages
    k_edge1<<<2048, 256, 0, stream>>>(x, ei, ea, A1, b1, h1);
    // 3) out = bias2 + h1 @ root2 (fully initializes d_out)
    k_node2<<<1024, 256, 0, stream>>>(h1, root2, bias2, out);
    // 4) out += scatter-add of layer-2 edge messages (quarter-slice, 2048 blocks)
    k_edge2<<<2048, 256, 0, stream>>>(h1, ei, ea, A2, b2, out);
}